// Round 1
// baseline (343.847 us; speedup 1.0000x reference)
//
#include <hip/hip_runtime.h>

#define B_   8
#define N_   1024
#define INF_ 128
#define H_   4
#define FH_  32
#define TI   16
#define NEG  0.2f

// ---------------------------------------------------------------------------
// Kernel 1: h = x @ W^T  (B*N x 128, K=128), plus src/dst projections.
// One block per 16 rows. W staged in LDS with stride 129 -> bank = (o+i)%32,
// conflict-free across lanes.
// ---------------------------------------------------------------------------
__global__ __launch_bounds__(256) void gat_h_kernel(
    const float* __restrict__ x,      // [B,N,128]
    const float* __restrict__ Ww,     // [128,128] (o-major)
    const float* __restrict__ attn,   // [4,65]
    float* __restrict__ hfeat,        // [B,N,128]
    float* __restrict__ srcv,         // [B,N,4]
    float* __restrict__ dstv)         // [B,N,4]
{
    __shared__ float W_lds[128 * 129];
    __shared__ float x_lds[TI][128];
    __shared__ float h_lds[TI][128];
    const int tid  = threadIdx.x;
    const int row0 = blockIdx.x * TI;

    #pragma unroll
    for (int k = 0; k < 64; ++k) {                 // 16384 floats of W
        int flat = tid + k * 256;
        W_lds[(flat >> 7) * 129 + (flat & 127)] = Ww[flat];
    }
    #pragma unroll
    for (int k = 0; k < 8; ++k) {                  // 2048 floats of x
        int flat = tid + k * 256;
        x_lds[flat >> 7][flat & 127] = x[(size_t)row0 * 128 + flat];
    }
    __syncthreads();

    #pragma unroll
    for (int k = 0; k < 8; ++k) {
        int task = tid + k * 256;                  // 2048 outputs
        int r = task >> 7, o = task & 127;
        const float* wrow = &W_lds[o * 129];
        const float* xrow = &x_lds[r][0];
        float acc = 0.f;
        #pragma unroll 8
        for (int i = 0; i < 128; ++i) acc = fmaf(xrow[i], wrow[i], acc);
        hfeat[(size_t)row0 * 128 + task] = acc;
        h_lds[r][o] = acc;
    }
    __syncthreads();

    if (tid < TI * 4) {                            // src/dst: 16 rows x 4 heads
        int r = tid >> 2, hh = tid & 3;
        float as = 0.f, ad = 0.f;
        #pragma unroll 8
        for (int f = 0; f < 32; ++f) {
            float hv = h_lds[r][hh * 32 + f];
            as = fmaf(hv, attn[hh * 65 + f], as);
            ad = fmaf(hv, attn[hh * 65 + 32 + f], ad);
        }
        srcv[(row0 + r) * 4 + hh] = as;
        dstv[(row0 + r) * 4 + hh] = ad;
    }
}

// ---------------------------------------------------------------------------
// Kernel 2: per (b, 16-i tile): online-softmax stats (pass A), then per 64-j
// tile recompute e -> alpha (write float4, stage in LDS) -> fp32 PV (pass B).
// ---------------------------------------------------------------------------
__global__ __launch_bounds__(256) void gat_attn_kernel(
    const float* __restrict__ adj,    // [B,N,N]
    const float* __restrict__ attn,   // [4,65]
    const float* __restrict__ hfeat,  // [B,N,128]
    const float* __restrict__ srcv,   // [B,N,4]
    const float* __restrict__ dstv,   // [B,N,4]
    float* __restrict__ out,          // [B,N,128]
    float* __restrict__ alpha)        // [B,N,N,4]
{
    __shared__ float dst_lds[N_ * 4];          // 16 KB
    __shared__ float src_lds[TI * 4];
    __shared__ float m_lds[TI][4];
    __shared__ float rs_lds[TI][4];
    __shared__ float redm[4][4], reds[4][4];   // [wave][h]
    __shared__ float alpha_lds[TI][64][4];     // 16 KB

    const int tid = threadIdx.x;
    const int b   = blockIdx.x >> 6;           // 64 tiles per batch
    const int i0  = (blockIdx.x & 63) * TI;
    const float NEGINF = -__builtin_inff();

    float a_e[4];
    #pragma unroll
    for (int h = 0; h < 4; ++h) a_e[h] = attn[h * 65 + 64];

    #pragma unroll
    for (int k = 0; k < 16; ++k) {             // dst for all j of this batch
        int flat = tid + k * 256;
        dst_lds[flat] = dstv[b * N_ * 4 + flat];
    }
    if (tid < TI * 4) src_lds[tid] = srcv[(b * N_ + i0) * 4 + tid];
    __syncthreads();

    // ---------------- Pass A: online max/sum per (i,h) ----------------
    for (int il = 0; il < TI; ++il) {
        const float* adj_row = adj + ((size_t)(b * N_ + i0 + il)) * N_;
        float m[4], s[4];
        #pragma unroll
        for (int h = 0; h < 4; ++h) { m[h] = NEGINF; s[h] = 0.f; }

        for (int j = tid; j < N_; j += 256) {
            float av = adj_row[j];
            if (av != 0.f) {
                #pragma unroll
                for (int h = 0; h < 4; ++h) {
                    float e = fmaf(av, a_e[h], src_lds[il * 4 + h] + dst_lds[j * 4 + h]);
                    e = e >= 0.f ? e : NEG * e;
                    float nm = fmaxf(m[h], e);
                    s[h] = s[h] * __expf(m[h] - nm) + __expf(e - nm);
                    m[h] = nm;
                }
            }
        }
        // reduce across 64 lanes, then across 4 waves
        #pragma unroll
        for (int h = 0; h < 4; ++h) {
            float mm = m[h], ss = s[h];
            #pragma unroll
            for (int off = 32; off > 0; off >>= 1) {
                float mo = __shfl_xor(mm, off);
                float so = __shfl_xor(ss, off);
                float nm = fmaxf(mm, mo);
                float ns = (nm == NEGINF) ? 0.f
                         : ss * __expf(mm - nm) + so * __expf(mo - nm);
                mm = nm; ss = ns;
            }
            if ((tid & 63) == 0) { redm[tid >> 6][h] = mm; reds[tid >> 6][h] = ss; }
        }
        __syncthreads();
        if (tid < 4) {
            float mm = NEGINF, ss = 0.f;
            #pragma unroll
            for (int w = 0; w < 4; ++w) {
                float mo = redm[w][tid], so = reds[w][tid];
                float nm = fmaxf(mm, mo);
                ss = (nm == NEGINF) ? 0.f
                   : ss * __expf(mm - nm) + so * __expf(mo - nm);
                mm = nm;
            }
            m_lds[il][tid]  = mm;
            rs_lds[il][tid] = (ss > 0.f) ? 1.f / ss : 0.f;
        }
        __syncthreads();
    }

    // ---------------- Pass B: alpha write + PV accumulate ----------------
    float acc[8];
    #pragma unroll
    for (int k = 0; k < 8; ++k) acc[k] = 0.f;
    const int hf   = tid & 127;    // (h,f) ownership for PV
    const int hh   = hf >> 5;
    const int half = tid >> 7;     // i-range split: 0..7 vs 8..15

    for (int jt = 0; jt < 16; ++jt) {
        const int j0 = jt * 64;
        // phase 1: alpha for 16i x 64j (4 tasks/thread), float4 store
        #pragma unroll
        for (int k = 0; k < 4; ++k) {
            int task = tid + k * 256;
            int il = task >> 6, jj = task & 63;
            int j  = j0 + jj;
            float av = adj[((size_t)(b * N_ + i0 + il)) * N_ + j];
            float4 al = make_float4(0.f, 0.f, 0.f, 0.f);
            if (av != 0.f) {
                float* alf = (float*)&al;
                #pragma unroll
                for (int h = 0; h < 4; ++h) {
                    float e = fmaf(av, a_e[h], src_lds[il * 4 + h] + dst_lds[j * 4 + h]);
                    e = e >= 0.f ? e : NEG * e;
                    alf[h] = __expf(e - m_lds[il][h]) * rs_lds[il][h];
                }
            }
            *(float4*)&alpha_lds[il][jj][0] = al;
            *(float4*)(alpha + (((size_t)(b * N_ + i0 + il)) * N_ + j) * 4) = al;
        }
        __syncthreads();
        // phase 2: PV — thread owns (h,f); 64 coalesced h reads, LDS broadcast
        const float* hrow = hfeat + ((size_t)(b * N_) + j0) * 128 + hf;
        #pragma unroll 4
        for (int jj = 0; jj < 64; ++jj) {
            float hv = hrow[(size_t)jj * 128];
            #pragma unroll
            for (int k = 0; k < 8; ++k)
                acc[k] = fmaf(alpha_lds[half * 8 + k][jj][hh], hv, acc[k]);
        }
        __syncthreads();
    }

    #pragma unroll
    for (int k = 0; k < 8; ++k) {
        int il = half * 8 + k;
        out[((size_t)(b * N_ + i0 + il)) * 128 + hf] = acc[k];
    }
}

extern "C" void kernel_launch(void* const* d_in, const int* in_sizes, int n_in,
                              void* d_out, int out_size, void* d_ws, size_t ws_size,
                              hipStream_t stream) {
    const float* x    = (const float*)d_in[0];
    const float* adj  = (const float*)d_in[1];
    const float* Ww   = (const float*)d_in[2];
    const float* attn = (const float*)d_in[3];

    float* out   = (float*)d_out;                       // [8,1024,128]
    float* alpha = out + (size_t)B_ * N_ * 128;         // [8,1024,1024,4]

    float* hfeat = (float*)d_ws;                        // 4 MB
    float* srcv  = hfeat + (size_t)B_ * N_ * 128;       // 128 KB
    float* dstv  = srcv + (size_t)B_ * N_ * 4;          // 128 KB

    gat_h_kernel<<<(B_ * N_) / TI, 256, 0, stream>>>(x, Ww, attn, hfeat, srcv, dstv);
    gat_attn_kernel<<<B_ * (N_ / TI), 256, 0, stream>>>(adj, attn, hfeat, srcv, dstv,
                                                        out, alpha);
}

// Round 2
// 320.015 us; speedup vs baseline: 1.0745x; 1.0745x over previous
//
#include <hip/hip_runtime.h>

#define NEG 0.2f
constexpr int B_ = 8, N_ = 1024;

// ---------------------------------------------------------------------------
// Kernel 1: h = x @ W^T (M=8192,N=128,K=128) + src/dst projections.
// 512 blocks x 256 threads, 16 rows/block. W in LDS (64KB, XOR-swizzled 16B
// blocks: elem W[c][i] at c*128 + ((i/4 ^ ((c>>2)&7))*4 + i%4) -> reads along
// i with lanes on c hit 8 bank-slots evenly). x read from global (L1 bcast).
// ---------------------------------------------------------------------------
__global__ __launch_bounds__(256) void gat_h_kernel(
    const float* __restrict__ x, const float* __restrict__ Ww,
    const float* __restrict__ attn,
    float* __restrict__ hfeat, float* __restrict__ srcv, float* __restrict__ dstv)
{
    __shared__ float Wl[128 * 128];
    const int tid = threadIdx.x;
    const int row0 = blockIdx.x * 16;

    #pragma unroll
    for (int k = 0; k < 16; ++k) {
        int f = tid + k * 256;
        int o = f >> 5, ib = f & 31;
        float4 w = *(const float4*)(Ww + o * 128 + ib * 4);
        *(float4*)&Wl[o * 128 + ((ib ^ ((o >> 2) & 7)) << 2)] = w;
    }
    __syncthreads();

    const int colg = tid & 31;   // 4 cols each: c = colg*4+cc
    const int rg   = tid >> 5;   // 8 groups x 2 rows
    const int swz  = colg & 7;
    float acc[2][4] = {};
    const float* xr = x + (size_t)(row0 + rg * 2) * 128;

    #pragma unroll 8
    for (int is = 0; is < 32; ++is) {
        float4 x0 = *(const float4*)(xr + is * 4);
        float4 x1 = *(const float4*)(xr + 128 + is * 4);
        #pragma unroll
        for (int cc = 0; cc < 4; ++cc) {
            float4 wv = *(const float4*)&Wl[(colg * 4 + cc) * 128 + ((is ^ swz) << 2)];
            acc[0][cc] = fmaf(x0.x, wv.x, acc[0][cc]);
            acc[0][cc] = fmaf(x0.y, wv.y, acc[0][cc]);
            acc[0][cc] = fmaf(x0.z, wv.z, acc[0][cc]);
            acc[0][cc] = fmaf(x0.w, wv.w, acc[0][cc]);
            acc[1][cc] = fmaf(x1.x, wv.x, acc[1][cc]);
            acc[1][cc] = fmaf(x1.y, wv.y, acc[1][cc]);
            acc[1][cc] = fmaf(x1.z, wv.z, acc[1][cc]);
            acc[1][cc] = fmaf(x1.w, wv.w, acc[1][cc]);
        }
    }
    #pragma unroll
    for (int r = 0; r < 2; ++r) {
        float4 hv = make_float4(acc[r][0], acc[r][1], acc[r][2], acc[r][3]);
        *(float4*)(hfeat + (size_t)(row0 + rg * 2 + r) * 128 + colg * 4) = hv;
    }
    // src/dst: head hh = colg>>3; reduce partials over the 8 colg lanes of hh.
    const int hh = colg >> 3;
    float ps[2] = {0.f, 0.f}, pd[2] = {0.f, 0.f};
    #pragma unroll
    for (int cc = 0; cc < 4; ++cc) {
        int fi = (colg & 7) * 4 + cc;
        float as = attn[hh * 65 + fi];
        float ad = attn[hh * 65 + 32 + fi];
        ps[0] = fmaf(acc[0][cc], as, ps[0]); ps[1] = fmaf(acc[1][cc], as, ps[1]);
        pd[0] = fmaf(acc[0][cc], ad, pd[0]); pd[1] = fmaf(acc[1][cc], ad, pd[1]);
    }
    #pragma unroll
    for (int m = 1; m <= 4; m <<= 1) {
        ps[0] += __shfl_xor(ps[0], m); ps[1] += __shfl_xor(ps[1], m);
        pd[0] += __shfl_xor(pd[0], m); pd[1] += __shfl_xor(pd[1], m);
    }
    if ((tid & 7) == 0) {
        #pragma unroll
        for (int r = 0; r < 2; ++r) {
            srcv[(size_t)(row0 + rg * 2 + r) * 4 + hh] = ps[r];
            dstv[(size_t)(row0 + rg * 2 + r) * 4 + hh] = pd[r];
        }
    }
}

// ---------------------------------------------------------------------------
// Kernel 2: 512 blocks (b, 16-row i-tile) x 512 threads (8 waves).
// Pass A: 2 rows/wave, sum-of-exp (no max needed: |e| <~ 8), shfl reduce.
// Per 64-j tile: stage h(swizzled)+adj -> phase1 alpha (LDS+global) ->
// outer-product PV: acc[8r][8c], jc=16-way j-split in lanes, shfl-reduced.
// ---------------------------------------------------------------------------
__global__ __launch_bounds__(512, 4) void gat_attn_kernel(
    const float* __restrict__ adj, const float* __restrict__ attn,
    const float* __restrict__ hfeat, const float* __restrict__ srcv,
    const float* __restrict__ dstv,
    float* __restrict__ out, float* __restrict__ alpha)
{
    __shared__ float src_l[64];
    __shared__ float rs_l[64];
    __shared__ float adj_t[16 * 68];      // [r][jj] pad 68
    __shared__ float al_l[4 * 64 * 20];   // [h][jj][r16 + pad4]
    __shared__ float h_t[64 * 128];       // [jj][c], 16B-blocks XOR (jj&7)

    const int tid  = threadIdx.x;
    const int lane = tid & 63;
    const int w    = tid >> 6;
    const int b    = blockIdx.x >> 6;
    const int i0   = (blockIdx.x & 63) * 16;

    float aE[4];
    #pragma unroll
    for (int h = 0; h < 4; ++h) aE[h] = attn[h * 65 + 64];

    if (tid < 64) src_l[tid] = srcv[(size_t)(b * N_ + i0) * 4 + tid];
    __syncthreads();

    // ---------------- Pass A: s = sum_j exp(leaky(e)) ----------------
    const float* dstb = dstv + (size_t)b * N_ * 4;
    #pragma unroll
    for (int rr = 0; rr < 2; ++rr) {
        int row = w * 2 + rr;
        const float* arow = adj + ((size_t)(b * N_ + i0 + row)) * N_;
        float sd[4];
        #pragma unroll
        for (int h = 0; h < 4; ++h) sd[h] = src_l[row * 4 + h];
        float s[4] = {0.f, 0.f, 0.f, 0.f};
        #pragma unroll
        for (int k = 0; k < 4; ++k) {
            float4 av4 = *(const float4*)(arow + lane * 4 + k * 256);
            const float* avp = (const float*)&av4;
            #pragma unroll
            for (int q = 0; q < 4; ++q) {
                float av = avp[q];
                if (av != 0.f) {
                    int j = lane * 4 + k * 256 + q;
                    float4 dv = *(const float4*)(dstb + j * 4);
                    const float* dvp = (const float*)&dv;
                    #pragma unroll
                    for (int h = 0; h < 4; ++h) {
                        float e = fmaf(av, aE[h], sd[h] + dvp[h]);
                        e = e >= 0.f ? e : NEG * e;
                        s[h] += __expf(e);
                    }
                }
            }
        }
        #pragma unroll
        for (int m = 1; m <= 32; m <<= 1) {
            #pragma unroll
            for (int h = 0; h < 4; ++h) s[h] += __shfl_xor(s[h], m);
        }
        if (lane == 0) {
            #pragma unroll
            for (int h = 0; h < 4; ++h)
                rs_l[row * 4 + h] = s[h] > 0.f ? 1.f / s[h] : 0.f;
        }
    }

    // ---------------- Main loop over 16 j-tiles ----------------
    const int rhalf  = w & 1;          // rows rhalf*8 .. +7
    const int hh     = w >> 1;         // head
    const int hf8low = (lane >> 4) & 3;
    const int jc     = lane & 15;
    float4 acc[8][2];
    #pragma unroll
    for (int r = 0; r < 8; ++r) {
        acc[r][0] = make_float4(0.f, 0.f, 0.f, 0.f);
        acc[r][1] = make_float4(0.f, 0.f, 0.f, 0.f);
    }

    for (int jt = 0; jt < 16; ++jt) {
        const int j0 = jt * 64;
        __syncthreads();
        // stage h tile (swizzled)
        #pragma unroll
        for (int k = 0; k < 4; ++k) {
            int f = tid + k * 512;
            int jj = f >> 5, cb = f & 31;
            float4 hv = *(const float4*)(hfeat + (size_t)(b * N_ + j0 + jj) * 128 + cb * 4);
            *(float4*)&h_t[jj * 128 + ((cb ^ (jj & 7)) << 2)] = hv;
        }
        // stage adj tile
        if (tid < 256) {
            int r = tid >> 4, q = tid & 15;
            float4 av4 = *(const float4*)(adj + ((size_t)(b * N_ + i0 + r)) * N_ + j0 + q * 4);
            *(float4*)&adj_t[r * 68 + q * 4] = av4;
        }
        __syncthreads();
        // phase 1: alpha = exp(leaky(e)) * rs  (write LDS + global)
        #pragma unroll
        for (int t = 0; t < 2; ++t) {
            int task = tid + t * 512;
            int r = task & 15, jj = task >> 4;
            float av = adj_t[r * 68 + jj];
            float4 al = make_float4(0.f, 0.f, 0.f, 0.f);
            if (av != 0.f) {
                float4 dv = *(const float4*)(dstb + (j0 + jj) * 4);
                const float* dvp = (const float*)&dv;
                float* alp = (float*)&al;
                #pragma unroll
                for (int h = 0; h < 4; ++h) {
                    float e = fmaf(av, aE[h], src_l[r * 4 + h] + dvp[h]);
                    e = e >= 0.f ? e : NEG * e;
                    alp[h] = __expf(e) * rs_l[r * 4 + h];
                }
            }
            const float* alp = (const float*)&al;
            #pragma unroll
            for (int h = 0; h < 4; ++h)
                al_l[h * 1280 + jj * 20 + r] = alp[h];
            *(float4*)(alpha + ((size_t)(b * N_ + i0 + r) * N_ + j0 + jj) * 4) = al;
        }
        __syncthreads();
        // phase 2: outer-product PV
        #pragma unroll
        for (int s = 0; s < 4; ++s) {
            int jj = s * 16 + jc;
            float4 aA = *(const float4*)&al_l[hh * 1280 + jj * 20 + rhalf * 8];
            float4 aB = *(const float4*)&al_l[hh * 1280 + jj * 20 + rhalf * 8 + 4];
            int cb0 = hh * 8 + hf8low * 2;
            float4 v0 = *(const float4*)&h_t[jj * 128 + ((cb0 ^ (jj & 7)) << 2)];
            float4 v1 = *(const float4*)&h_t[jj * 128 + (((cb0 + 1) ^ (jj & 7)) << 2)];
#define PVROW(RR, AV)                                                    \
            acc[RR][0].x = fmaf(AV, v0.x, acc[RR][0].x);                 \
            acc[RR][0].y = fmaf(AV, v0.y, acc[RR][0].y);                 \
            acc[RR][0].z = fmaf(AV, v0.z, acc[RR][0].z);                 \
            acc[RR][0].w = fmaf(AV, v0.w, acc[RR][0].w);                 \
            acc[RR][1].x = fmaf(AV, v1.x, acc[RR][1].x);                 \
            acc[RR][1].y = fmaf(AV, v1.y, acc[RR][1].y);                 \
            acc[RR][1].z = fmaf(AV, v1.z, acc[RR][1].z);                 \
            acc[RR][1].w = fmaf(AV, v1.w, acc[RR][1].w);
            PVROW(0, aA.x) PVROW(1, aA.y) PVROW(2, aA.z) PVROW(3, aA.w)
            PVROW(4, aB.x) PVROW(5, aB.y) PVROW(6, aB.z) PVROW(7, aB.w)
#undef PVROW
        }
    }

    // reduce over the 16 jc lanes (lane bits 0..3), all-lanes valid after
    #pragma unroll
    for (int m = 1; m <= 8; m <<= 1) {
        #pragma unroll
        for (int r = 0; r < 8; ++r) {
            #pragma unroll
            for (int c = 0; c < 2; ++c) {
                acc[r][c].x += __shfl_xor(acc[r][c].x, m);
                acc[r][c].y += __shfl_xor(acc[r][c].y, m);
                acc[r][c].z += __shfl_xor(acc[r][c].z, m);
                acc[r][c].w += __shfl_xor(acc[r][c].w, m);
            }
        }
    }
    // each jc lane stores one (row, 4-col) quad; static indices only
    #pragma unroll
    for (int r = 0; r < 8; ++r) {
        #pragma unroll
        for (int c = 0; c < 2; ++c) {
            if ((jc >> 1) == r && (jc & 1) == c) {
                int orow = i0 + rhalf * 8 + r;
                int ocol = hh * 32 + hf8low * 8 + c * 4;
                *(float4*)(out + (size_t)(b * N_ + orow) * 128 + ocol) = acc[r][c];
            }
        }
    }
}

extern "C" void kernel_launch(void* const* d_in, const int* in_sizes, int n_in,
                              void* d_out, int out_size, void* d_ws, size_t ws_size,
                              hipStream_t stream) {
    const float* x    = (const float*)d_in[0];
    const float* adj  = (const float*)d_in[1];
    const float* Ww   = (const float*)d_in[2];
    const float* attn = (const float*)d_in[3];

    float* out   = (float*)d_out;                    // [8,1024,128]
    float* alpha = out + (size_t)B_ * N_ * 128;      // [8,1024,1024,4]

    float* hfeat = (float*)d_ws;                     // 4 MB
    float* srcv  = hfeat + (size_t)B_ * N_ * 128;
    float* dstv  = srcv + (size_t)B_ * N_ * 4;

    gat_h_kernel<<<512, 256, 0, stream>>>(x, Ww, attn, hfeat, srcv, dstv);
    gat_attn_kernel<<<512, 512, 0, stream>>>(adj, attn, hfeat, srcv, dstv, out, alpha);
}

// Round 3
// 279.906 us; speedup vs baseline: 1.2284x; 1.1433x over previous
//
#include <hip/hip_runtime.h>

#define NEG 0.2f
constexpr int B_ = 8, N_ = 1024;

// ---------------------------------------------------------------------------
// Kernel 1: h = x @ W^T (M=8192,N=128,K=128) + src/dst projections.
// (unchanged from round 2 — a few µs, not the bottleneck)
// ---------------------------------------------------------------------------
__global__ __launch_bounds__(256) void gat_h_kernel(
    const float* __restrict__ x, const float* __restrict__ Ww,
    const float* __restrict__ attn,
    float* __restrict__ hfeat, float* __restrict__ srcv, float* __restrict__ dstv)
{
    __shared__ float Wl[128 * 128];
    const int tid = threadIdx.x;
    const int row0 = blockIdx.x * 16;

    #pragma unroll
    for (int k = 0; k < 16; ++k) {
        int f = tid + k * 256;
        int o = f >> 5, ib = f & 31;
        float4 w = *(const float4*)(Ww + o * 128 + ib * 4);
        *(float4*)&Wl[o * 128 + ((ib ^ ((o >> 2) & 7)) << 2)] = w;
    }
    __syncthreads();

    const int colg = tid & 31;
    const int rg   = tid >> 5;
    const int swz  = colg & 7;
    float acc[2][4] = {};
    const float* xr = x + (size_t)(row0 + rg * 2) * 128;

    #pragma unroll 8
    for (int is = 0; is < 32; ++is) {
        float4 x0 = *(const float4*)(xr + is * 4);
        float4 x1 = *(const float4*)(xr + 128 + is * 4);
        #pragma unroll
        for (int cc = 0; cc < 4; ++cc) {
            float4 wv = *(const float4*)&Wl[(colg * 4 + cc) * 128 + ((is ^ swz) << 2)];
            acc[0][cc] = fmaf(x0.x, wv.x, acc[0][cc]);
            acc[0][cc] = fmaf(x0.y, wv.y, acc[0][cc]);
            acc[0][cc] = fmaf(x0.z, wv.z, acc[0][cc]);
            acc[0][cc] = fmaf(x0.w, wv.w, acc[0][cc]);
            acc[1][cc] = fmaf(x1.x, wv.x, acc[1][cc]);
            acc[1][cc] = fmaf(x1.y, wv.y, acc[1][cc]);
            acc[1][cc] = fmaf(x1.z, wv.z, acc[1][cc]);
            acc[1][cc] = fmaf(x1.w, wv.w, acc[1][cc]);
        }
    }
    #pragma unroll
    for (int r = 0; r < 2; ++r) {
        float4 hv = make_float4(acc[r][0], acc[r][1], acc[r][2], acc[r][3]);
        *(float4*)(hfeat + (size_t)(row0 + rg * 2 + r) * 128 + colg * 4) = hv;
    }
    const int hh = colg >> 3;
    float ps[2] = {0.f, 0.f}, pd[2] = {0.f, 0.f};
    #pragma unroll
    for (int cc = 0; cc < 4; ++cc) {
        int fi = (colg & 7) * 4 + cc;
        float as = attn[hh * 65 + fi];
        float ad = attn[hh * 65 + 32 + fi];
        ps[0] = fmaf(acc[0][cc], as, ps[0]); ps[1] = fmaf(acc[1][cc], as, ps[1]);
        pd[0] = fmaf(acc[0][cc], ad, pd[0]); pd[1] = fmaf(acc[1][cc], ad, pd[1]);
    }
    #pragma unroll
    for (int m = 1; m <= 4; m <<= 1) {
        ps[0] += __shfl_xor(ps[0], m); ps[1] += __shfl_xor(ps[1], m);
        pd[0] += __shfl_xor(pd[0], m); pd[1] += __shfl_xor(pd[1], m);
    }
    if ((tid & 7) == 0) {
        #pragma unroll
        for (int r = 0; r < 2; ++r) {
            srcv[(size_t)(row0 + rg * 2 + r) * 4 + hh] = ps[r];
            dstv[(size_t)(row0 + rg * 2 + r) * 4 + hh] = pd[r];
        }
    }
}

// ---------------------------------------------------------------------------
// Kernel 2: 512 blocks x 512 threads. b = bid&7 -> XCD-local hfeat (4MB/XCD L2).
// Pass A: sum-of-exp per (i,h), shfl-reduced. Per 64-j tile:
//   stage h (swizzled 16B blocks) ->
//   phase1: alpha; jj=lane, r=wave+8t -> 1KB contiguous global stores;
//           LDS al_l[h][jj][r] stride 21 (odd -> conflict-free writes,
//           broadcast reads) ->
//   phase2: outer-product PV acc[8r][8c], jc=16-way j-split, shfl-reduced.
// ---------------------------------------------------------------------------
__global__ __launch_bounds__(512, 4) void gat_attn_kernel(
    const float* __restrict__ adj, const float* __restrict__ attn,
    const float* __restrict__ hfeat, const float* __restrict__ srcv,
    const float* __restrict__ dstv,
    float* __restrict__ out, float* __restrict__ alpha)
{
    __shared__ float src_l[64];
    __shared__ float rs_l[64];
    __shared__ float al_l[4 * 64 * 21];   // [h][jj][r], stride 21
    __shared__ float h_t[64 * 128];       // [jj][c], 16B blocks XOR (jj&7)

    const int tid  = threadIdx.x;
    const int lane = tid & 63;
    const int w    = tid >> 6;
    const int b    = blockIdx.x & 7;            // XCD-local batch
    const int i0   = (blockIdx.x >> 3) * 16;

    float aE[4];
    #pragma unroll
    for (int h = 0; h < 4; ++h) aE[h] = attn[h * 65 + 64];

    if (tid < 64) src_l[tid] = srcv[(size_t)(b * N_ + i0) * 4 + tid];
    __syncthreads();

    // ---------------- Pass A: s = sum_j exp(leaky(e)) ----------------
    const float* dstb = dstv + (size_t)b * N_ * 4;
    #pragma unroll
    for (int rr = 0; rr < 2; ++rr) {
        int row = w * 2 + rr;
        const float* arow = adj + ((size_t)(b * N_ + i0 + row)) * N_;
        float sd[4];
        #pragma unroll
        for (int h = 0; h < 4; ++h) sd[h] = src_l[row * 4 + h];
        float s[4] = {0.f, 0.f, 0.f, 0.f};
        #pragma unroll
        for (int k = 0; k < 4; ++k) {
            float4 av4 = *(const float4*)(arow + lane * 4 + k * 256);
            const float* avp = (const float*)&av4;
            #pragma unroll
            for (int q = 0; q < 4; ++q) {
                float av = avp[q];
                if (av != 0.f) {
                    int j = lane * 4 + k * 256 + q;
                    float4 dv = *(const float4*)(dstb + j * 4);
                    const float* dvp = (const float*)&dv;
                    #pragma unroll
                    for (int h = 0; h < 4; ++h) {
                        float e = fmaf(av, aE[h], sd[h] + dvp[h]);
                        e = e >= 0.f ? e : NEG * e;
                        s[h] += __expf(e);
                    }
                }
            }
        }
        #pragma unroll
        for (int m = 1; m <= 32; m <<= 1) {
            #pragma unroll
            for (int h = 0; h < 4; ++h) s[h] += __shfl_xor(s[h], m);
        }
        if (lane == 0) {
            #pragma unroll
            for (int h = 0; h < 4; ++h)
                rs_l[row * 4 + h] = s[h] > 0.f ? 1.f / s[h] : 0.f;
        }
    }

    // ---------------- Main loop over 16 j-tiles ----------------
    const int rhalf  = w & 1;
    const int hh     = w >> 1;
    const int hf8low = (lane >> 4) & 3;
    const int jc     = lane & 15;
    float4 acc[8][2];
    #pragma unroll
    for (int r = 0; r < 8; ++r) {
        acc[r][0] = make_float4(0.f, 0.f, 0.f, 0.f);
        acc[r][1] = make_float4(0.f, 0.f, 0.f, 0.f);
    }

    for (int jt = 0; jt < 16; ++jt) {
        const int j0 = jt * 64;
        __syncthreads();                   // h_t/al_l free of prev readers
        // stage h tile (swizzled)
        #pragma unroll
        for (int k = 0; k < 4; ++k) {
            int f = tid + k * 512;
            int jj = f >> 5, cb = f & 31;
            float4 hv = *(const float4*)(hfeat + (size_t)(b * N_ + j0 + jj) * 128 + cb * 4);
            *(float4*)&h_t[jj * 128 + ((cb ^ (jj & 7)) << 2)] = hv;
        }
        // phase 1: alpha -> LDS + coalesced global (jj = lane)
        #pragma unroll
        for (int t = 0; t < 2; ++t) {
            int r = w + t * 8;
            float av = adj[((size_t)(b * N_ + i0 + r)) * N_ + j0 + lane];
            float4 al = make_float4(0.f, 0.f, 0.f, 0.f);
            if (av != 0.f) {
                float4 dv = *(const float4*)(dstb + (j0 + lane) * 4);
                const float* dvp = (const float*)&dv;
                float* alp = (float*)&al;
                #pragma unroll
                for (int h = 0; h < 4; ++h) {
                    float e = fmaf(av, aE[h], src_l[r * 4 + h] + dvp[h]);
                    e = e >= 0.f ? e : NEG * e;
                    alp[h] = __expf(e) * rs_l[r * 4 + h];
                }
            }
            const float* alp = (const float*)&al;
            #pragma unroll
            for (int h = 0; h < 4; ++h)
                al_l[h * 1344 + lane * 21 + r] = alp[h];
            *(float4*)(alpha + (((size_t)(b * N_ + i0 + r)) * N_ + j0 + lane) * 4) = al;
        }
        __syncthreads();
        // phase 2: outer-product PV
        #pragma unroll
        for (int s = 0; s < 4; ++s) {
            int jj = s * 16 + jc;
            const float* ab = &al_l[hh * 1344 + jj * 21 + rhalf * 8];
            float av8[8];
            #pragma unroll
            for (int ri = 0; ri < 8; ++ri) av8[ri] = ab[ri];
            int cb0 = hh * 8 + hf8low * 2;
            float4 v0 = *(const float4*)&h_t[jj * 128 + ((cb0 ^ (jj & 7)) << 2)];
            float4 v1 = *(const float4*)&h_t[jj * 128 + (((cb0 + 1) ^ (jj & 7)) << 2)];
#define PVROW(RR, AV)                                                    \
            acc[RR][0].x = fmaf(AV, v0.x, acc[RR][0].x);                 \
            acc[RR][0].y = fmaf(AV, v0.y, acc[RR][0].y);                 \
            acc[RR][0].z = fmaf(AV, v0.z, acc[RR][0].z);                 \
            acc[RR][0].w = fmaf(AV, v0.w, acc[RR][0].w);                 \
            acc[RR][1].x = fmaf(AV, v1.x, acc[RR][1].x);                 \
            acc[RR][1].y = fmaf(AV, v1.y, acc[RR][1].y);                 \
            acc[RR][1].z = fmaf(AV, v1.z, acc[RR][1].z);                 \
            acc[RR][1].w = fmaf(AV, v1.w, acc[RR][1].w);
            PVROW(0, av8[0]) PVROW(1, av8[1]) PVROW(2, av8[2]) PVROW(3, av8[3])
            PVROW(4, av8[4]) PVROW(5, av8[5]) PVROW(6, av8[6]) PVROW(7, av8[7])
#undef PVROW
        }
    }

    // reduce over the 16 jc lanes
    #pragma unroll
    for (int m = 1; m <= 8; m <<= 1) {
        #pragma unroll
        for (int r = 0; r < 8; ++r) {
            #pragma unroll
            for (int c = 0; c < 2; ++c) {
                acc[r][c].x += __shfl_xor(acc[r][c].x, m);
                acc[r][c].y += __shfl_xor(acc[r][c].y, m);
                acc[r][c].z += __shfl_xor(acc[r][c].z, m);
                acc[r][c].w += __shfl_xor(acc[r][c].w, m);
            }
        }
    }
    #pragma unroll
    for (int r = 0; r < 8; ++r) {
        #pragma unroll
        for (int c = 0; c < 2; ++c) {
            if ((jc >> 1) == r && (jc & 1) == c) {
                int orow = i0 + rhalf * 8 + r;
                int ocol = hh * 32 + hf8low * 8 + c * 4;
                *(float4*)(out + (size_t)(b * N_ + orow) * 128 + ocol) = acc[r][c];
            }
        }
    }
}

extern "C" void kernel_launch(void* const* d_in, const int* in_sizes, int n_in,
                              void* d_out, int out_size, void* d_ws, size_t ws_size,
                              hipStream_t stream) {
    const float* x    = (const float*)d_in[0];
    const float* adj  = (const float*)d_in[1];
    const float* Ww   = (const float*)d_in[2];
    const float* attn = (const float*)d_in[3];

    float* out   = (float*)d_out;                    // [8,1024,128]
    float* alpha = out + (size_t)B_ * N_ * 128;      // [8,1024,1024,4]

    float* hfeat = (float*)d_ws;                     // 4 MB
    float* srcv  = hfeat + (size_t)B_ * N_ * 128;
    float* dstv  = srcv + (size_t)B_ * N_ * 4;

    gat_h_kernel<<<512, 256, 0, stream>>>(x, Ww, attn, hfeat, srcv, dstv);
    gat_attn_kernel<<<512, 512, 0, stream>>>(adj, attn, hfeat, srcv, dstv, out, alpha);
}